// Round 9
// baseline (947.967 us; speedup 1.0000x reference)
//
#include <hip/hip_runtime.h>
#include <hip/hip_bf16.h>
#include <math.h>
#include <stdint.h>

#define NPTS 4096
#define CIN 64
#define COUT 64
#define BATCH 8
#define KNN 20
#define NSEL 8              // 8 chunks of 512 candidates
#define SCH (NPTS / NSEL)   // 512
#define STILE 64            // re-pin row4 every 64 candidates

// Scalar-pipe (constant addrspace) types: loads compile to s_load_* and the
// values feed VALU as the 1-allowed-SGPR operand (v_fmac v, s, v).
typedef float vf4 __attribute__((ext_vector_type(4)));
typedef __attribute__((address_space(4))) const vf4  cvf4;
typedef __attribute__((address_space(4))) const float cflt;

// ---------------------------------------------------------------------------
// K0: transpose x -> xT[b][n][c], xx[b][n] = sum_c x^2, and the two small
// GEMMs u[b][n][o] = sum_c (W[o,c]-W[o,64+c])*x[b,c,n],
//       v[b][n][o] = sum_c  W[o,64+c]      *x[b,c,n]
// (h[b,o,n,k] = u[b,n,o] + v[b,idx[b,n,k],o] by linearity of the edge-conv.)
// ---------------------------------------------------------------------------
__global__ __launch_bounds__(256) void k_prep(const float* __restrict__ x,
                                              const float* __restrict__ W,
                                              float* __restrict__ xT,
                                              float* __restrict__ xx,
                                              float* __restrict__ u,
                                              float* __restrict__ v) {
    __shared__ float xs[64][65];   // [c][j], padded: transpose read is conflict-free
    __shared__ float wd[64][64];   // [c][o] = W1 - W2
    __shared__ float wv[64][64];   // [c][o] = W2
    const int t = threadIdx.x;
    const int b = blockIdx.y;
    const int n0 = blockIdx.x * 64;

    const float* xb = x + (size_t)b * CIN * NPTS;
#pragma unroll
    for (int i = 0; i < 16; ++i) {          // load x tile, coalesced per c-row
        int flat = t + 256 * i;             // 4096 elements
        int c = flat >> 6, j = flat & 63;
        xs[c][j] = xb[(size_t)c * NPTS + n0 + j];
    }
#pragma unroll
    for (int i = 0; i < 16; ++i) {          // load/transform W (32 KB, L2-cached)
        int flat = t + 256 * i;
        int o = flat & 63, c = flat >> 6;
        float w1 = W[o * 128 + c];
        float w2 = W[o * 128 + 64 + c];
        wd[c][o] = w1 - w2;
        wv[c][o] = w2;
    }
    __syncthreads();

#pragma unroll
    for (int i = 0; i < 16; ++i) {          // write xT, coalesced over c
        int flat = t + 256 * i;
        int j = flat >> 6, c = flat & 63;
        xT[((size_t)b * NPTS + n0 + j) * 64 + c] = xs[c][j];
    }
    if (t < 64) {                           // xx: sequential over c
        float s = 0.f;
#pragma unroll
        for (int c = 0; c < 64; ++c) { float a = xs[c][t]; s += a * a; }
        xx[b * NPTS + n0 + t] = s;
    }

    // u, v: each thread owns channel o = t&63 for 16 point-columns j = (t>>6)+4i
    const int o = t & 63, jb = t >> 6;
    float au[16], av[16];
#pragma unroll
    for (int i = 0; i < 16; ++i) { au[i] = 0.f; av[i] = 0.f; }
    for (int c = 0; c < 64; ++c) {
        float a = wd[c][o];                 // consecutive o -> conflict-free (2-way, free)
        float p = wv[c][o];
#pragma unroll
        for (int i = 0; i < 16; ++i) {
            float xc = xs[c][jb + 4 * i];   // wave-uniform -> LDS broadcast
            au[i] += a * xc;
            av[i] += p * xc;
        }
    }
#pragma unroll
    for (int i = 0; i < 16; ++i) {
        int j = jb + 4 * i;
        size_t base = ((size_t)b * NPTS + n0 + j) * 64 + o;
        u[base] = au[i];                    // coalesced over o
        v[base] = av[i];
    }
}

// ---------------------------------------------------------------------------
// K1: fused distance + top-20, SCALAR-PIPE candidate stream.
// R8 diagnosis: the LDS broadcast (16 ds_read_b128/cand, 16B unique per read)
// costs ~192 cyc/cand of per-CU LDS pipe = ~656us aggregate == measured 673us
// -> LDS-pipe-bound. Fix: candidate row + xx read via AS4 (constant
// addrspace) pointers -> s_load_* on the scalar/SMEM pipe; each FMA is
// v_fmac v, s, v (1 SGPR operand, legal). No LDS, no barriers.
// NSEL=8 -> 1024 blocks = 4 waves/SIMD to hide s_load latency.
// Chain branchless (was taken ~100% anyway; med3 chain is idempotent for
// d <= vals[19]) -- selection semantics bit-identical to R5/R8 passing runs.
// b = bid&7 = XCD id under hw round-robin: one batch's 1MB xT per L2.
// ---------------------------------------------------------------------------
__global__ __launch_bounds__(256, 2) void k_knn(const float* __restrict__ xT,
                                                const float* __restrict__ xx,
                                                float* __restrict__ cval,
                                                int* __restrict__ cidx) {
    const int t = threadIdx.x;
    const int bid = blockIdx.x + 16 * (blockIdx.y + NSEL * blockIdx.z);
    const int b = bid & 7;                  // XCD id under hw round-robin
    const int slot = bid >> 3;              // 0..127
    const int chunk = slot & (NSEL - 1);    // 0..7
    const int rowgrp = slot >> 3;           // 0..15
    const int n = rowgrp * 256 + t;
    const int m0 = chunk * SCH;

    const float* xTb = xT + (size_t)b * NPTS * 64;

    // row -> registers, pinned (compiler otherwise remats/parks the loads)
    float4 row4[16];
    const float4* rp = (const float4*)(xTb + (size_t)n * 64);
#pragma unroll
    for (int q = 0; q < 16; ++q) row4[q] = rp[q];
#pragma unroll
    for (int q = 0; q < 16; ++q) {
        asm volatile("" : "+v"(row4[q].x), "+v"(row4[q].y),
                          "+v"(row4[q].z), "+v"(row4[q].w));
    }

    float vals[KNN];
    int   idxs[KNN];
#pragma unroll
    for (int k = 0; k < KNN; ++k) { vals[k] = -INFINITY; idxs[k] = -1; }

    // wave-uniform candidate stream through the scalar pipe (AS4)
    cvf4* colp = (cvf4*)(uintptr_t)(xTb + (size_t)m0 * 64);
    cflt* xxp  = (cflt*)(uintptr_t)(xx + b * NPTS + m0);

    for (int T = 0; T < SCH / STILE; ++T) {
        // re-pin row4 once per 64 candidates: bounds any spill/remat traffic
#pragma unroll
        for (int q = 0; q < 16; ++q) {
            asm volatile("" : "+v"(row4[q].x), "+v"(row4[q].y),
                              "+v"(row4[q].z), "+v"(row4[q].w));
        }
#pragma unroll 2
        for (int mi = 0; mi < STILE; ++mi) {
            const int mm = T * STILE + mi;
            float a0 = 0.f, a1 = 0.f, a2 = 0.f, a3 = 0.f;
#pragma unroll
            for (int q = 0; q < 16; ++q) {
                vf4 c4 = colp[mm * 16 + q];     // s_load; SGPR operands below
                a0 += row4[q].x * c4.x;
                a1 += row4[q].y * c4.y;
                a2 += row4[q].z * c4.z;
                a3 += row4[q].w * c4.w;
            }
            float inner = (a0 + a1) + (a2 + a3);
            float d = 2.f * inner - xxp[mm];
            const int midx = m0 + mm;
            bool c[KNN];
#pragma unroll
            for (int k = 0; k < KNN; ++k) c[k] = (vals[k] >= d);  // old vals
#pragma unroll
            for (int j = KNN - 1; j >= 1; --j) {
                vals[j] = __builtin_amdgcn_fmed3f(d, vals[j - 1], vals[j]);
                idxs[j] = c[j] ? idxs[j] : (c[j - 1] ? midx : idxs[j - 1]);
            }
            vals[0] = fmaxf(vals[0], d);
            idxs[0] = c[0] ? idxs[0] : midx;
        }
    }

    size_t rbase = ((size_t)(b * NPTS + n) * NSEL + chunk) * KNN;
#pragma unroll
    for (int k = 0; k < KNN; ++k) { cval[rbase + k] = vals[k]; cidx[rbase + k] = idxs[k]; }
}

// ---------------------------------------------------------------------------
// K2: NC-way merge of per-chunk sorted top-20 lists. Strict '>' keeps the
// lowest chunk on ties (chunks cover ascending m) = lowest-index-first.
// ---------------------------------------------------------------------------
template <int NC>
__global__ __launch_bounds__(256) void k_merge(const float* __restrict__ cval,
                                               const int* __restrict__ cidx,
                                               int* __restrict__ idxf) {
    const int r = blockIdx.x * 256 + threadIdx.x;   // 0..B*N-1
    const float* v0 = cval + (size_t)r * (NC * KNN);
    const int*   i0 = cidx + (size_t)r * (NC * KNN);
    int p[NC];
#pragma unroll
    for (int c = 0; c < NC; ++c) p[c] = 0;
    int* op = idxf + (size_t)r * KNN;
    for (int k = 0; k < KNN; ++k) {
        float best = -INFINITY; int besti = 0, bc = 0;
#pragma unroll
        for (int c = 0; c < NC; ++c) {
            float hv = v0[c * KNN + p[c]];          // L1-cached re-reads
            int   hi = i0[c * KNN + p[c]];
            bool g = hv > best;
            best = g ? hv : best;
            besti = g ? hi : besti;
            bc = g ? c : bc;
        }
        op[k] = besti;
#pragma unroll
        for (int c = 0; c < NC; ++c) p[c] += (bc == c);
    }
}

// ---------------------------------------------------------------------------
// K4: single gather pass: h = u[n][o] + v[m][o]; accumulate sum/sumsq per
// channel (block partials, no atomics -> deterministic) and per-(n,o) max/min.
// ---------------------------------------------------------------------------
__global__ __launch_bounds__(256) void k_gather(const float* __restrict__ u,
                                                const float* __restrict__ v,
                                                const int* __restrict__ idxf,
                                                float* __restrict__ hmax,
                                                float* __restrict__ hmin,
                                                float* __restrict__ part) {
    const int t = threadIdx.x;
    const int o = t & 63, w = t >> 6;
    const int b = blockIdx.y;
    const int n0 = blockIdx.x * 64;
    const float* vb = v + (size_t)b * NPTS * 64;
    float su = 0.f, sq = 0.f;
    for (int r = 0; r < 16; ++r) {
        int n = n0 + w + 4 * r;
        size_t nb = (size_t)b * NPTS + n;
        float hu = u[nb * 64 + o];
        const int* ip = idxf + nb * KNN;    // wave-uniform reads
        float mx = -INFINITY, mn = INFINITY;
#pragma unroll 4
        for (int k = 0; k < KNN; ++k) {
            int m = ip[k];
            float h = hu + vb[(size_t)m * 64 + o];
            mx = fmaxf(mx, h);
            mn = fminf(mn, h);
            su += h;
            sq += h * h;
        }
        hmax[nb * 64 + o] = mx;
        hmin[nb * 64 + o] = mn;
    }
    __shared__ float red[4][128];
    red[w][o] = su;
    red[w][64 + o] = sq;
    __syncthreads();
    if (t < 128) {
        float s = red[0][t] + red[1][t] + red[2][t] + red[3][t];
        part[(size_t)(blockIdx.y * 64 + blockIdx.x) * 128 + t] = s;
    }
}

// ---------------------------------------------------------------------------
// K5: reduce 512 block partials -> mean/var -> fused scale/shift.
// ---------------------------------------------------------------------------
__global__ __launch_bounds__(256) void k_stats(const float* __restrict__ part,
                                               const float* __restrict__ gamma,
                                               const float* __restrict__ beta,
                                               float* __restrict__ ab) {
    __shared__ float rs[4][64], rq[4][64];
    const int t = threadIdx.x;
    const int o = t & 63, sl = t >> 6;      // 4 slices of 128 rows
    float s = 0.f, q = 0.f;
    for (int r = sl; r < 512; r += 4) {
        s += part[r * 128 + o];
        q += part[r * 128 + 64 + o];
    }
    rs[sl][o] = s; rq[sl][o] = q;
    __syncthreads();
    if (t < 64) {
        float ss = rs[0][t] + rs[1][t] + rs[2][t] + rs[3][t];
        float qq = rq[0][t] + rq[1][t] + rq[2][t] + rq[3][t];
        const float cnt = (float)BATCH * NPTS * KNN;
        float mean = ss / cnt;
        float var = qq / cnt - mean * mean;
        float rstd = rsqrtf(var + 1e-5f);
        float a = gamma[t] * rstd;
        ab[t] = a;
        ab[64 + t] = beta[t] - mean * a;
    }
}

// ---------------------------------------------------------------------------
// K6: epilogue. Monotone affine+LeakyReLU => max over k is at hmax (scale>=0)
// or hmin (scale<0). LDS transpose for coalesced out[b][o][n] writes.
// ---------------------------------------------------------------------------
__global__ __launch_bounds__(256) void k_out(const float* __restrict__ hmax,
                                             const float* __restrict__ hmin,
                                             const float* __restrict__ ab,
                                             float* __restrict__ out) {
    __shared__ float ts[64][65];
    const int t = threadIdx.x;
    const int b = blockIdx.y;
    const int n0 = blockIdx.x * 64;
#pragma unroll
    for (int i = 0; i < 16; ++i) {
        int flat = t + 256 * i;
        int j = flat >> 6, o = flat & 63;
        size_t nb = ((size_t)b * NPTS + n0 + j) * 64 + o;
        float a = ab[o], sh = ab[64 + o];
        float hval = (a >= 0.f) ? hmax[nb] : hmin[nb];
        float val = a * hval + sh;
        val = (val >= 0.f) ? val : 0.2f * val;
        ts[o][j] = val;
    }
    __syncthreads();
#pragma unroll
    for (int i = 0; i < 16; ++i) {
        int flat = t + 256 * i;
        int o = flat >> 6, j = flat & 63;
        out[((size_t)b * 64 + o) * NPTS + n0 + j] = ts[o][j];
    }
}

// ---------------------------------------------------------------------------
extern "C" void kernel_launch(void* const* d_in, const int* in_sizes, int n_in,
                              void* d_out, int out_size, void* d_ws, size_t ws_size,
                              hipStream_t stream) {
    const float* x     = (const float*)d_in[0];   // (8, 64, 4096)
    const float* W     = (const float*)d_in[1];   // (64, 128)
    const float* gamma = (const float*)d_in[2];   // (64,)
    const float* beta  = (const float*)d_in[3];   // (64,)
    float* out = (float*)d_out;                   // (8, 64, 4096)

    float* ws = (float*)d_ws;
    const size_t BN = (size_t)BATCH * NPTS;       // 32768
    size_t off = 0;
    float* xT   = ws + off; off += BN * 64;
    float* xx   = ws + off; off += BN;
    float* u    = ws + off; off += BN * 64;
    float* v    = ws + off; off += BN * 64;
    float* cval = ws + off; off += BN * NSEL * KNN;
    int*   cidx = (int*)(ws + off); off += BN * NSEL * KNN;
    int*   idxf = (int*)(ws + off); off += BN * KNN;
    float* hmx  = ws + off; off += BN * 64;
    float* hmn  = ws + off; off += BN * 64;
    float* part = ws + off; off += 512 * 128;
    float* ab   = ws + off; off += 128;
    // ~87 MB total; fits the ws_size that R8 proved is < 624 MB but >= R8's use.

    k_prep <<<dim3(64, BATCH), 256, 0, stream>>>(x, W, xT, xx, u, v);
    k_knn  <<<dim3(16, NSEL, BATCH), 256, 0, stream>>>(xT, xx, cval, cidx);
    k_merge<NSEL><<<dim3((int)(BN / 256)), 256, 0, stream>>>(cval, cidx, idxf);
    k_gather<<<dim3(64, BATCH), 256, 0, stream>>>(u, v, idxf, hmx, hmn, part);
    k_stats<<<1, 256, 0, stream>>>(part, gamma, beta, ab);
    k_out  <<<dim3(64, BATCH), 256, 0, stream>>>(hmx, hmn, ab, out);
}

// Round 12
// 657.303 us; speedup vs baseline: 1.4422x; 1.4422x over previous
//
#include <hip/hip_runtime.h>
#include <hip/hip_bf16.h>
#include <math.h>
#include <stdint.h>

#define NPTS 4096
#define CIN 64
#define COUT 64
#define BATCH 8
#define KNN 20
#define NSEL 8              // 8 chunks of 512 candidates
#define SCH (NPTS / NSEL)   // 512
#define DEPTH 16            // LDS stack depth per thread

// Scalar-pipe (constant addrspace) types: loads compile to s_load_* and the
// values feed VALU as the 1-allowed-SGPR operand (v_fmac v, s, v).
typedef float vf4 __attribute__((ext_vector_type(4)));
typedef __attribute__((address_space(4))) const vf4  cvf4;
typedef __attribute__((address_space(4))) const float cflt;

// ---------------------------------------------------------------------------
// K0: transpose x -> xT[b][n][c], xx[b][n] = sum_c x^2, and the two small
// GEMMs u[b][n][o] = sum_c (W[o,c]-W[o,64+c])*x[b,c,n],
//       v[b][n][o] = sum_c  W[o,64+c]      *x[b,c,n]
// (h[b,o,n,k] = u[b,n,o] + v[b,idx[b,n,k],o] by linearity of the edge-conv.)
// ---------------------------------------------------------------------------
__global__ __launch_bounds__(256) void k_prep(const float* __restrict__ x,
                                              const float* __restrict__ W,
                                              float* __restrict__ xT,
                                              float* __restrict__ xx,
                                              float* __restrict__ u,
                                              float* __restrict__ v) {
    __shared__ float xs[64][65];   // [c][j], padded: transpose read is conflict-free
    __shared__ float wd[64][64];   // [c][o] = W1 - W2
    __shared__ float wv[64][64];   // [c][o] = W2
    const int t = threadIdx.x;
    const int b = blockIdx.y;
    const int n0 = blockIdx.x * 64;

    const float* xb = x + (size_t)b * CIN * NPTS;
#pragma unroll
    for (int i = 0; i < 16; ++i) {          // load x tile, coalesced per c-row
        int flat = t + 256 * i;             // 4096 elements
        int c = flat >> 6, j = flat & 63;
        xs[c][j] = xb[(size_t)c * NPTS + n0 + j];
    }
#pragma unroll
    for (int i = 0; i < 16; ++i) {          // load/transform W (32 KB, L2-cached)
        int flat = t + 256 * i;
        int o = flat & 63, c = flat >> 6;
        float w1 = W[o * 128 + c];
        float w2 = W[o * 128 + 64 + c];
        wd[c][o] = w1 - w2;
        wv[c][o] = w2;
    }
    __syncthreads();

#pragma unroll
    for (int i = 0; i < 16; ++i) {          // write xT, coalesced over c
        int flat = t + 256 * i;
        int j = flat >> 6, c = flat & 63;
        xT[((size_t)b * NPTS + n0 + j) * 64 + c] = xs[c][j];
    }
    if (t < 64) {                           // xx: sequential over c
        float s = 0.f;
#pragma unroll
        for (int c = 0; c < 64; ++c) { float a = xs[c][t]; s += a * a; }
        xx[b * NPTS + n0 + t] = s;
    }

    // u, v: each thread owns channel o = t&63 for 16 point-columns j = (t>>6)+4i
    const int o = t & 63, jb = t >> 6;
    float au[16], av[16];
#pragma unroll
    for (int i = 0; i < 16; ++i) { au[i] = 0.f; av[i] = 0.f; }
    for (int c = 0; c < 64; ++c) {
        float a = wd[c][o];                 // consecutive o -> conflict-free (2-way, free)
        float p = wv[c][o];
#pragma unroll
        for (int i = 0; i < 16; ++i) {
            float xc = xs[c][jb + 4 * i];   // wave-uniform -> LDS broadcast
            au[i] += a * xc;
            av[i] += p * xc;
        }
    }
#pragma unroll
    for (int i = 0; i < 16; ++i) {
        int j = jb + 4 * i;
        size_t base = ((size_t)b * NPTS + n0 + j) * 64 + o;
        u[base] = au[i];                    // coalesced over o
        v[base] = av[i];
    }
}

// ---------------------------------------------------------------------------
// K1: fused distance + top-20 = scalar-pipe stream + threshold/stack filter.
// Hot loop per candidate: 64 FMA (c4 via s_load, SGPR operand) + d-calc +
// 1 cmp + predicated LDS push (~75 inst vs R8/R9's ~170: the 105-inst med3
// chain now runs only on pushes, ~600/row vs 4096/row). Selection is exactly
// equivalent: push predicate is the same strict d > vals[19] with a stale
// (only-looser) threshold; chain processes entries in stream order and is a
// no-op for d <= current vals[19]. Overflow: check every 8 cands,
// __any(sp > 8) -> flush (growth <= 8/check, DEPTH=16 -> max index 15).
// vals/idxs are now COLD (touched only in flush) -> AGPR parking harmless.
// (256,4): 4 waves/SIMD to hide the s_load stream (R9 was 2 -> 277us stall).
// b = bid&7 = XCD id under hw round-robin: one batch's 1MB xT per L2.
// ---------------------------------------------------------------------------
__global__ __launch_bounds__(256, 4) void k_knn(const float* __restrict__ xT,
                                                const float* __restrict__ xx,
                                                float* __restrict__ cval,
                                                int* __restrict__ cidx) {
    __shared__ float2 stk[DEPTH][256];      // 32 KB: per-thread stacks, lane-consecutive
    const int t = threadIdx.x;
    const int bid = blockIdx.x + 16 * (blockIdx.y + NSEL * blockIdx.z);
    const int b = bid & 7;                  // XCD id under hw round-robin
    const int slot = bid >> 3;              // 0..127
    const int chunk = slot & (NSEL - 1);    // 0..7
    const int rowgrp = slot >> 3;           // 0..15
    const int n = rowgrp * 256 + t;
    const int m0 = chunk * SCH;

    const float* xTb = xT + (size_t)b * NPTS * 64;

    // row -> registers, pinned (compiler otherwise remats/parks the loads)
    float4 row4[16];
    const float4* rp = (const float4*)(xTb + (size_t)n * 64);
#pragma unroll
    for (int q = 0; q < 16; ++q) row4[q] = rp[q];
#pragma unroll
    for (int q = 0; q < 16; ++q) {
        asm volatile("" : "+v"(row4[q].x), "+v"(row4[q].y),
                          "+v"(row4[q].z), "+v"(row4[q].w));
    }

    float vals[KNN];
    int   idxs[KNN];
#pragma unroll
    for (int k = 0; k < KNN; ++k) { vals[k] = -INFINITY; idxs[k] = -1; }

    // wave-uniform candidate stream through the scalar pipe (AS4)
    cvf4* colp = (cvf4*)(uintptr_t)(xTb + (size_t)m0 * 64);
    cflt* xxp  = (cflt*)(uintptr_t)(xx + b * NPTS + m0);

    float thr = -INFINITY;                  // stale copy of vals[19]
    int sp = 0;

    auto flush = [&]() {
        for (int i = 0; i < sp; ++i) {      // divergent; bounded by wave-max sp
            float2 e = stk[i][t];
            float d = e.x;
            int midx = __float_as_int(e.y);
            bool c[KNN];
#pragma unroll
            for (int k = 0; k < KNN; ++k) c[k] = (vals[k] >= d);  // old vals
#pragma unroll
            for (int j = KNN - 1; j >= 1; --j) {
                vals[j] = __builtin_amdgcn_fmed3f(d, vals[j - 1], vals[j]);
                idxs[j] = c[j] ? idxs[j] : (c[j - 1] ? midx : idxs[j - 1]);
            }
            vals[0] = fmaxf(vals[0], d);
            idxs[0] = c[0] ? idxs[0] : midx;
        }
        sp = 0;
        thr = vals[KNN - 1];
    };

    for (int T = 0; T < SCH / 64; ++T) {
        // re-pin row4 once per 64 candidates: bounds any spill/remat traffic
#pragma unroll
        for (int q = 0; q < 16; ++q) {
            asm volatile("" : "+v"(row4[q].x), "+v"(row4[q].y),
                              "+v"(row4[q].z), "+v"(row4[q].w));
        }
        for (int g = 0; g < 8; ++g) {
#pragma unroll
            for (int mi = 0; mi < 8; ++mi) {
                const int mm = T * 64 + g * 8 + mi;
                float a0 = 0.f, a1 = 0.f, a2 = 0.f, a3 = 0.f;
#pragma unroll
                for (int q = 0; q < 16; ++q) {
                    vf4 c4 = colp[mm * 16 + q];     // s_load; SGPR operand in FMA
                    a0 += row4[q].x * c4.x;
                    a1 += row4[q].y * c4.y;
                    a2 += row4[q].z * c4.z;
                    a3 += row4[q].w * c4.w;
                }
                float inner = (a0 + a1) + (a2 + a3);
                float d = 2.f * inner - xxp[mm];
                if (d > thr) {              // same strict predicate as old chain gate
                    stk[sp][t] = make_float2(d, __int_as_float(m0 + mm));
                    ++sp;
                }
            }
            if (__any(sp > 8)) flush();     // growth <= 8 per check -> no overflow
        }
    }
    flush();                                // drain

    size_t rbase = ((size_t)(b * NPTS + n) * NSEL + chunk) * KNN;
#pragma unroll
    for (int k = 0; k < KNN; ++k) { cval[rbase + k] = vals[k]; cidx[rbase + k] = idxs[k]; }
}

// ---------------------------------------------------------------------------
// K2: NC-way merge, register-resident heads (R9 version re-read all NC heads
// from global every output: 320 loads/row; now 1 val + 1 idx reload per
// output = 56 loads/row). Strict '>' with ascending c keeps the lowest chunk
// on ties (chunks cover ascending m) = lowest-index-first, as before.
// ---------------------------------------------------------------------------
template <int NC>
__global__ __launch_bounds__(256) void k_merge(const float* __restrict__ cval,
                                               const int* __restrict__ cidx,
                                               int* __restrict__ idxf) {
    const int r = blockIdx.x * 256 + threadIdx.x;   // 0..B*N-1
    const float* v0 = cval + (size_t)r * (NC * KNN);
    const int*   i0 = cidx + (size_t)r * (NC * KNN);
    float hv[NC]; int hi[NC]; int hp[NC];
#pragma unroll
    for (int c = 0; c < NC; ++c) { hp[c] = 0; hv[c] = v0[c * KNN]; hi[c] = i0[c * KNN]; }
    int* op = idxf + (size_t)r * KNN;
    for (int k = 0; k < KNN; ++k) {
        float best = hv[0]; int bi = hi[0], bc = 0;
#pragma unroll
        for (int c = 1; c < NC; ++c) {
            bool g = hv[c] > best;
            best = g ? hv[c] : best;
            bi = g ? hi[c] : bi;
            bc = g ? c : bc;
        }
        op[k] = bi;
        int np = hp[bc] + 1;                // advance consumed list only
        bool ok = np < KNN;
        float nv = ok ? v0[bc * KNN + np] : -INFINITY;
        int   ni = ok ? i0[bc * KNN + np] : -1;
#pragma unroll
        for (int c = 0; c < NC; ++c) {      // static-index update (no scratch)
            bool upd = (c == bc);
            hp[c] = upd ? np : hp[c];
            hv[c] = upd ? nv : hv[c];
            hi[c] = upd ? ni : hi[c];
        }
    }
}

// ---------------------------------------------------------------------------
// K4: single gather pass: h = u[n][o] + v[m][o]; accumulate sum/sumsq per
// channel (block partials, no atomics -> deterministic) and per-(n,o) max/min.
// b = bid&7: batch-per-XCD (v[b] = 1 MB fits one L2; without swizzle all
// 8 MB of v lands on every XCD's 4 MB L2).
// ---------------------------------------------------------------------------
__global__ __launch_bounds__(256) void k_gather(const float* __restrict__ u,
                                                const float* __restrict__ v,
                                                const int* __restrict__ idxf,
                                                float* __restrict__ hmax,
                                                float* __restrict__ hmin,
                                                float* __restrict__ part) {
    const int t = threadIdx.x;
    const int o = t & 63, w = t >> 6;
    const int bid = blockIdx.x + 64 * blockIdx.y;
    const int b = bid & 7;                  // XCD id under hw round-robin
    const int n0 = (bid >> 3) * 64;         // 0..63 -> n-block
    const float* vb = v + (size_t)b * NPTS * 64;
    float su = 0.f, sq = 0.f;
    for (int r = 0; r < 16; ++r) {
        int n = n0 + w + 4 * r;
        size_t nb = (size_t)b * NPTS + n;
        float hu = u[nb * 64 + o];
        const int* ip = idxf + nb * KNN;    // wave-uniform reads
        float mx = -INFINITY, mn = INFINITY;
#pragma unroll 4
        for (int k = 0; k < KNN; ++k) {
            int m = ip[k];
            float h = hu + vb[(size_t)m * 64 + o];
            mx = fmaxf(mx, h);
            mn = fminf(mn, h);
            su += h;
            sq += h * h;
        }
        hmax[nb * 64 + o] = mx;
        hmin[nb * 64 + o] = mn;
    }
    __shared__ float red[4][128];
    red[w][o] = su;
    red[w][64 + o] = sq;
    __syncthreads();
    if (t < 128) {
        float s = red[0][t] + red[1][t] + red[2][t] + red[3][t];
        part[(size_t)(blockIdx.y * 64 + blockIdx.x) * 128 + t] = s;
    }
}

// ---------------------------------------------------------------------------
// K5: reduce 512 block partials -> mean/var -> fused scale/shift.
// ---------------------------------------------------------------------------
__global__ __launch_bounds__(256) void k_stats(const float* __restrict__ part,
                                               const float* __restrict__ gamma,
                                               const float* __restrict__ beta,
                                               float* __restrict__ ab) {
    __shared__ float rs[4][64], rq[4][64];
    const int t = threadIdx.x;
    const int o = t & 63, sl = t >> 6;      // 4 slices of 128 rows
    float s = 0.f, q = 0.f;
    for (int r = sl; r < 512; r += 4) {
        s += part[r * 128 + o];
        q += part[r * 128 + 64 + o];
    }
    rs[sl][o] = s; rq[sl][o] = q;
    __syncthreads();
    if (t < 64) {
        float ss = rs[0][t] + rs[1][t] + rs[2][t] + rs[3][t];
        float qq = rq[0][t] + rq[1][t] + rq[2][t] + rq[3][t];
        const float cnt = (float)BATCH * NPTS * KNN;
        float mean = ss / cnt;
        float var = qq / cnt - mean * mean;
        float rstd = rsqrtf(var + 1e-5f);
        float a = gamma[t] * rstd;
        ab[t] = a;
        ab[64 + t] = beta[t] - mean * a;
    }
}

// ---------------------------------------------------------------------------
// K6: epilogue. Monotone affine+LeakyReLU => max over k is at hmax (scale>=0)
// or hmin (scale<0). LDS transpose for coalesced out[b][o][n] writes.
// ---------------------------------------------------------------------------
__global__ __launch_bounds__(256) void k_out(const float* __restrict__ hmax,
                                             const float* __restrict__ hmin,
                                             const float* __restrict__ ab,
                                             float* __restrict__ out) {
    __shared__ float ts[64][65];
    const int t = threadIdx.x;
    const int b = blockIdx.y;
    const int n0 = blockIdx.x * 64;
#pragma unroll
    for (int i = 0; i < 16; ++i) {
        int flat = t + 256 * i;
        int j = flat >> 6, o = flat & 63;
        size_t nb = ((size_t)b * NPTS + n0 + j) * 64 + o;
        float a = ab[o], sh = ab[64 + o];
        float hval = (a >= 0.f) ? hmax[nb] : hmin[nb];
        float val = a * hval + sh;
        val = (val >= 0.f) ? val : 0.2f * val;
        ts[o][j] = val;
    }
    __syncthreads();
#pragma unroll
    for (int i = 0; i < 16; ++i) {
        int flat = t + 256 * i;
        int o = flat >> 6, j = flat & 63;
        out[((size_t)b * 64 + o) * NPTS + n0 + j] = ts[o][j];
    }
}

// ---------------------------------------------------------------------------
extern "C" void kernel_launch(void* const* d_in, const int* in_sizes, int n_in,
                              void* d_out, int out_size, void* d_ws, size_t ws_size,
                              hipStream_t stream) {
    const float* x     = (const float*)d_in[0];   // (8, 64, 4096)
    const float* W     = (const float*)d_in[1];   // (64, 128)
    const float* gamma = (const float*)d_in[2];   // (64,)
    const float* beta  = (const float*)d_in[3];   // (64,)
    float* out = (float*)d_out;                   // (8, 64, 4096)

    float* ws = (float*)d_ws;
    const size_t BN = (size_t)BATCH * NPTS;       // 32768
    size_t off = 0;
    float* xT   = ws + off; off += BN * 64;
    float* xx   = ws + off; off += BN;
    float* u    = ws + off; off += BN * 64;
    float* v    = ws + off; off += BN * 64;
    float* cval = ws + off; off += BN * NSEL * KNN;
    int*   cidx = (int*)(ws + off); off += BN * NSEL * KNN;
    int*   idxf = (int*)(ws + off); off += BN * KNN;
    float* hmx  = ws + off; off += BN * 64;
    float* hmn  = ws + off; off += BN * 64;
    float* part = ws + off; off += 512 * 128;
    float* ab   = ws + off; off += 128;
    // ~87 MB total (same as the R9 passing run).

    k_prep <<<dim3(64, BATCH), 256, 0, stream>>>(x, W, xT, xx, u, v);
    k_knn  <<<dim3(16, NSEL, BATCH), 256, 0, stream>>>(xT, xx, cval, cidx);
    k_merge<NSEL><<<dim3((int)(BN / 256)), 256, 0, stream>>>(cval, cidx, idxf);
    k_gather<<<dim3(64, BATCH), 256, 0, stream>>>(u, v, idxf, hmx, hmn, part);
    k_stats<<<1, 256, 0, stream>>>(part, gamma, beta, ab);
    k_out  <<<dim3(64, BATCH), 256, 0, stream>>>(hmx, hmn, ab, out);
}